// Round 12
// baseline (127.843 us; speedup 1.0000x reference)
//
#include <hip/hip_runtime.h>
#include <hip/hip_bf16.h>

#define IN_C 64
#define OUT_C 64

typedef __attribute__((ext_vector_type(8))) short bf16x8;
typedef __attribute__((ext_vector_type(4))) float f32x4;

// fp32 -> bf16 (RNE), bit-level, finite inputs
__device__ __forceinline__ short f2bf(float f) {
    unsigned u = __float_as_uint(f);
    unsigned r = (u + 0x7FFFu + ((u >> 16) & 1u)) >> 16;
    return (short)r;
}

// -------- Kernel 1 (fused): MFMA GEMM h = bf16(x@W) + CSR rowptr build ---
// Blocks [0, gemm_blocks): 4 waves/block, each wave = one 16-node M-tile.
//   W staged ONCE per block into LDS in fragment-ready bf16 layout:
//   wlds[(ks*4+nt)*64 + g*16 + m] = {W[ks*32+g*8+j][nt*16+m], j=0..7} (16 B).
//   Per wave: 8 ds_read_b128 for B, 4 float4 loads + 48 cvt for A, 8 MFMA.
//   C layout (m89-verified): col=lane&15, row=(lane>>4)*4+reg.
// Blocks [gemm_blocks, ...): rowptr fill, 4 edges/thread via int4.
__global__ __launch_bounds__(256) void gcn_prep_kernel(
    const float* __restrict__ x, const float* __restrict__ w,
    unsigned short* __restrict__ h,
    const int* __restrict__ row, int* __restrict__ rowptr,
    int n_nodes, int n_edges, int gemm_blocks) {
    if ((int)blockIdx.x < gemm_blocks) {
        __shared__ bf16x8 wlds[512];   // 8 KB, fragment-ready bf16 W
        const int tid  = threadIdx.x;
        const int lane = tid & 63;
        const int wv   = tid >> 6;
        const int m    = lane & 15;    // node-in-tile / B col / C col
        const int g    = lane >> 4;    // k-group

        // cooperative W stage: coalesced global read, fragment-layout LDS write
        #pragma unroll
        for (int i = tid; i < IN_C * OUT_C; i += 256) {
            const int k = i >> 6, c = i & 63;
            const int ks = k >> 5, gg = (k >> 3) & 3, j = k & 7;
            const int nt = c >> 4, mm = c & 15;
            ((short*)wlds)[((ks * 4 + nt) * 64 + gg * 16 + mm) * 8 + j] =
                f2bf(w[i]);
        }
        __syncthreads();

        const int node0 = ((int)blockIdx.x * 4 + wv) * 16;
        if (node0 >= n_nodes) return;

        // B frags from LDS: one ds_read_b128 each
        bf16x8 bfr[2][4];
        #pragma unroll
        for (int ks = 0; ks < 2; ++ks) {
            #pragma unroll
            for (int nt = 0; nt < 4; ++nt) {
                bfr[ks][nt] = wlds[(ks * 4 + nt) * 64 + g * 16 + m];
            }
        }

        // A frags: elem j of frag[ks] = x[node0+m][ks*32 + g*8 + j]
        const int arow = min(node0 + m, n_nodes - 1);
        const float* xr = x + (size_t)arow * IN_C;
        bf16x8 afr[2];
        #pragma unroll
        for (int ks = 0; ks < 2; ++ks) {
            const float4 p0 = *(const float4*)(xr + ks * 32 + g * 8);
            const float4 p1 = *(const float4*)(xr + ks * 32 + g * 8 + 4);
            union { short s[8]; bf16x8 v; } u;
            u.s[0] = f2bf(p0.x); u.s[1] = f2bf(p0.y);
            u.s[2] = f2bf(p0.z); u.s[3] = f2bf(p0.w);
            u.s[4] = f2bf(p1.x); u.s[5] = f2bf(p1.y);
            u.s[6] = f2bf(p1.z); u.s[7] = f2bf(p1.w);
            afr[ks] = u.v;
        }

        f32x4 acc[4];
        #pragma unroll
        for (int nt = 0; nt < 4; ++nt) acc[nt] = (f32x4){0.f, 0.f, 0.f, 0.f};
        #pragma unroll
        for (int ks = 0; ks < 2; ++ks) {
            #pragma unroll
            for (int nt = 0; nt < 4; ++nt) {
                acc[nt] = __builtin_amdgcn_mfma_f32_16x16x32_bf16(
                    afr[ks], bfr[ks][nt], acc[nt], 0, 0, 0);
            }
        }

        // C store: reg j -> node = node0 + g*4 + j, channel = nt*16 + m
        #pragma unroll
        for (int j = 0; j < 4; ++j) {
            const int node = node0 + g * 4 + j;
            if (node < n_nodes) {
                #pragma unroll
                for (int nt = 0; nt < 4; ++nt) {
                    h[(size_t)node * OUT_C + nt * 16 + m] =
                        (unsigned short)f2bf(acc[nt][j]);
                }
            }
        }
    } else {
        // rowptr: 4 edges per thread (n_edges % 4 == 0 in this problem;
        // guarded anyway)
        const int t  = ((int)blockIdx.x - gemm_blocks) * 256 + threadIdx.x;
        const int e0 = t * 4;
        if (e0 >= n_edges) return;
        const int4 r4 = *(const int4*)(row + e0);
        int rprev = (e0 == 0) ? -1 : row[e0 - 1];
        int rr[4] = {r4.x, r4.y, r4.z, r4.w};
        #pragma unroll
        for (int i = 0; i < 4; ++i) {
            if (e0 + i < n_edges) {
                for (int n = rprev + 1; n <= rr[i]; ++n) rowptr[n] = e0 + i;
                rprev = rr[i];
            }
        }
        if (e0 + 4 >= n_edges) {   // last thread: close out the tail
            for (int n = rprev + 1; n <= n_nodes; ++n) rowptr[n] = n_edges;
        }
    }
}

// -------- Kernel 2: bf16 segment-sum + degree scale + bias --------
// 8 lanes per node (lane owns 8 bf16 channels = one uint4 of the h row),
// 8 nodes per wave, 32 nodes per 256-thread block. No cross-lane reduce.
// Unroll-16 with clamped edge indices: 16 independent col loads then 16
// independent 16 B gathers in flight per lane; avg degree 16 -> most nodes
// finish in ONE batch (halves dependent chains + wave-divergence penalty).
#define UNPACK_ADD(v)                                   \
    do {                                                \
        acc[0] += __uint_as_float((v).x << 16);         \
        acc[1] += __uint_as_float((v).x & 0xFFFF0000u); \
        acc[2] += __uint_as_float((v).y << 16);         \
        acc[3] += __uint_as_float((v).y & 0xFFFF0000u); \
        acc[4] += __uint_as_float((v).z << 16);         \
        acc[5] += __uint_as_float((v).z & 0xFFFF0000u); \
        acc[6] += __uint_as_float((v).w << 16);         \
        acc[7] += __uint_as_float((v).w & 0xFFFF0000u); \
    } while (0)

__global__ __launch_bounds__(256) void gcn_agg_kernel(
    const uint4* __restrict__ h4, const int* __restrict__ col,
    const int* __restrict__ rowptr, const float* __restrict__ deg,
    const float4* __restrict__ bias4, float4* __restrict__ out4,
    int n_nodes) {
    const int tid  = threadIdx.x;
    const int node = blockIdx.x * 32 + (tid >> 3);   // 8 lanes per node
    if (node >= n_nodes) return;
    const int lo   = tid & 7;                        // channel octet

    const int begin = rowptr[node];
    const int end   = rowptr[node + 1];
    const int last  = end - 1;

    float acc[8] = {0.f, 0.f, 0.f, 0.f, 0.f, 0.f, 0.f, 0.f};
    for (int e = begin; e < end; e += 16) {
        int c[16];
        #pragma unroll
        for (int i = 0; i < 16; ++i) c[i] = col[min(e + i, last)];
        uint4 v[16];
        #pragma unroll
        for (int i = 0; i < 16; ++i) v[i] = h4[(size_t)c[i] * 8 + lo];
        UNPACK_ADD(v[0]);
        #pragma unroll
        for (int i = 1; i < 16; ++i) {
            if (e + i <= last) UNPACK_ADD(v[i]);
        }
    }

    const float  d  = deg[node];
    const float4 b0 = bias4[lo * 2];
    const float4 b1 = bias4[lo * 2 + 1];
    float4 oa, ob;
    oa.x = fmaf(acc[0], d, b0.x);
    oa.y = fmaf(acc[1], d, b0.y);
    oa.z = fmaf(acc[2], d, b0.z);
    oa.w = fmaf(acc[3], d, b0.w);
    ob.x = fmaf(acc[4], d, b1.x);
    ob.y = fmaf(acc[5], d, b1.y);
    ob.z = fmaf(acc[6], d, b1.z);
    ob.w = fmaf(acc[7], d, b1.w);
    out4[(size_t)node * 16 + lo * 2]     = oa;
    out4[(size_t)node * 16 + lo * 2 + 1] = ob;
}

extern "C" void kernel_launch(void* const* d_in, const int* in_sizes, int n_in,
                              void* d_out, int out_size, void* d_ws, size_t ws_size,
                              hipStream_t stream) {
    const float* x    = (const float*)d_in[0];
    const float* w    = (const float*)d_in[1];
    const float* bias = (const float*)d_in[2];
    const int* col    = (const int*)d_in[3];
    const int* row    = (const int*)d_in[4];
    const float* deg  = (const float*)d_in[5];

    const int n_nodes = in_sizes[5];     // degrees: [N_NODES]
    const int n_edges = in_sizes[3];     // column_index: [N_EDGES]

    unsigned short* h = (unsigned short*)d_ws;            // N*64 bf16 = 12.8 MB
    int* rowptr = (int*)((char*)d_ws +
                         (size_t)n_nodes * OUT_C * sizeof(unsigned short));

    const int gemm_blocks   = (n_nodes + 63) / 64;        // 64 nodes/block
    const int rowptr_blocks = (n_edges + 1023) / 1024;    // 4 edges/thread
    gcn_prep_kernel<<<gemm_blocks + rowptr_blocks, 256, 0, stream>>>(
        x, w, h, row, rowptr, n_nodes, n_edges, gemm_blocks);

    const int agg_blocks = (n_nodes + 31) / 32;           // 32 nodes per block
    gcn_agg_kernel<<<agg_blocks, 256, 0, stream>>>(
        (const uint4*)h, col, rowptr, deg,
        (const float4*)bias, (float4*)d_out, n_nodes);
}